// Round 10
// baseline (415.156 us; speedup 1.0000x reference)
//
#include <hip/hip_runtime.h>

#define VOCAB 50257
#define NB 512
#define NT 2048
#define NOUT 128
#define CHUNK 32
#define L2E 1.4426950408889634f
#define INV2L2E 0.34657359027997264f   // 1/(2*log2e) = ln2/2

#define QP_XOR1 0xB1   // quad_perm [1,0,3,2]
#define QP_PAIR 0xA0   // quad_perm [0,0,2,2]
#define QP_CROSS 0x0A  // quad_perm [2,2,0,0]

template<int CTRL>
__device__ __forceinline__ float qp(float v){
    return __int_as_float(__builtin_amdgcn_update_dpp(0, __float_as_int(v), CTRL, 0xF, 0xF, true));
}

// K1: tab[v][p], p=0..7 -> gate rows perm={i0,f0,g0,o0,i1,f1,g1,o1} with folded
// scale: -log2e for sigmoid rows (i,f,o), +2log2e for tanh rows (g).
__global__ __launch_bounds__(256) void build_table(const float* __restrict__ emb,
                                                   const float* __restrict__ Wih0,
                                                   const float* __restrict__ b0,
                                                   float* __restrict__ tab){
    int v = blockIdx.x*256 + threadIdx.x;
    if (v >= VOCAB) return;
    const float4* ep = (const float4*)(emb + (size_t)v*8);
    float4 e0 = ep[0], e1 = ep[1];
    float e[8] = {e0.x,e0.y,e0.z,e0.w,e1.x,e1.y,e1.z,e1.w};
    const int perm[8] = {0,2,4,6,1,3,5,7};
    float o[8];
#pragma unroll
    for (int p=0;p<8;p++){
        int rj = perm[p];
        float s = b0[rj];
#pragma unroll
        for (int d=0;d<8;d++) s = fmaf(e[d], Wih0[rj*8+d], s);
        o[p] = s * ((rj==4||rj==5) ? 2.0f*L2E : -L2E);
    }
    float4* tp = (float4*)(tab + (size_t)v*8);
    tp[0] = make_float4(o[0],o[1],o[2],o[3]);
    tp[1] = make_float4(o[4],o[5],o[6],o[7]);
}

// K1b: gx[t][b][0..7] = tab[x[b][t]][0..7] — parallel gather on all CUs.
__global__ __launch_bounds__(256) void expand_gates(const int* __restrict__ x,
                                                    const float* __restrict__ tab,
                                                    float4* __restrict__ gx){
    int gid = blockIdx.x*256 + threadIdx.x;   // [0, B*T)
    int t = gid >> 9;
    int b = gid & (NB-1);
    int tok = x[(size_t)b*NT + t];
    const float4* tp = (const float4*)tab + (size_t)tok*2;
    float4 v0 = tp[0], v1 = tp[1];
    gx[(size_t)gid*2]   = v0;
    gx[(size_t)gid*2+1] = v1;
}

// Uniform gate nonlinearity + quad combine, c kept pre-scaled by 2*log2e
// (so tanh(c) needs no mul before exp2). Lane l of a quad: l0:(i0,f0)
// l1:(g0,o0) l2:(i1,f1) l3:(g1,o1). Valid c on lanes 0,2.
// CC/HS/HO are per-rowset state variable names.
#define GATE_COMBINE(x0, x1, CC, HS, HO) { \
    float ex0 = __builtin_amdgcn_exp2f(x0); \
    float ex1 = __builtin_amdgcn_exp2f(x1); \
    float r0 = __builtin_amdgcn_rcpf(1.0f+ex0); \
    float r1 = __builtin_amdgcn_rcpf(1.0f+ex1); \
    float v0 = fmaf(B0, r0, A0); \
    float u0 = qp<QP_XOR1>(v0); \
    float u1 = qp<QP_XOR1>(r1); \
    CC = fmaf(r1, CC, v0*u0); \
    float e2c = __builtin_amdgcn_exp2f(CC); \
    float th = fmaf(-2.0f, __builtin_amdgcn_rcpf(1.0f+e2c), 1.0f); \
    float hh = u1*th; \
    HS = qp<QP_PAIR>(hh); \
    HO = qp<QP_CROSS>(hh); }

// K2: layer-pipelined scan, 4 lanes/row, TWO interleaved rowsets per wave
// (quad q owns rows q and q+16 — independent dep chains hide each other's
// latency). Block = 128 thr = 2 waves; wave0=layer0, wave1=layer1.
__global__ __launch_bounds__(128) void lstm_pipe(const float2* __restrict__ gx,
                                                 const float* __restrict__ Whh0,
                                                 const float* __restrict__ Wih1,
                                                 const float* __restrict__ Whh1,
                                                 const float* __restrict__ b1,
                                                 float* __restrict__ y1out,   // [T][B][2]
                                                 float* __restrict__ tail){
    __shared__ float h0buf[2][CHUNK][32][2];   // 16 KB double buffer
    const int tid  = threadIdx.x;
    const int wv   = tid >> 6;
    const int lane = tid & 63;
    const int l    = lane & 3;
    const int q    = lane >> 2;               // 0..15
    const int rowA = blockIdx.x*32 + q;
    const int rowB = rowA + 16;
    const int e    = l >> 1;
    const int rj0  = (l&1)*4 + e;             // i or g row
    const int rj1  = rj0 + 2;                 // f or o row
    const float s0 = (l&1) ? 2.0f*L2E : -L2E;
    const float s1 = -L2E;
    const float A0 = (l&1) ? 2.0f*L2E : 0.0f;   // tanh map pre-scaled by 2L2E
    const float B0 = (l&1) ? -4.0f*L2E : 1.0f;

    // wave0 weights (layer 0)
    const float wS0 = Whh0[rj0*2+e]*s0,  wO0 = Whh0[rj0*2+(e^1)]*s0;
    const float wS1 = Whh0[rj1*2+e]*s1,  wO1 = Whh0[rj1*2+(e^1)]*s1;
    // wave1 weights (layer 1)
    const float wi00 = Wih1[rj0*2+0]*s0, wi01 = Wih1[rj0*2+1]*s0;
    const float wi10 = Wih1[rj1*2+0]*s1, wi11 = Wih1[rj1*2+1]*s1;
    const float whS0 = Whh1[rj0*2+e]*s0, whO0 = Whh1[rj0*2+(e^1)]*s0;
    const float whS1 = Whh1[rj1*2+e]*s1, whO1 = Whh1[rj1*2+(e^1)]*s1;
    const float bb0  = b1[rj0]*s0,       bb1  = b1[rj1]*s1;

    float hsA=0.f, hoA=0.f, cA=0.f;
    float hsB=0.f, hoB=0.f, cB=0.f;
    const size_t ST = (size_t)NB*4;           // float2 stride per t
    const float2* __restrict__ gpA = gx + (size_t)rowA*4 + l;
    const float2* __restrict__ gpB = gx + (size_t)rowB*4 + l;
    float2 a0,a1,a2,a3, b0v,b1v,b2v,b3v;      // 4-deep prefetch per rowset
    if (wv==0){
        a0=gpA[0*ST]; a1=gpA[1*ST]; a2=gpA[2*ST]; a3=gpA[3*ST];
        b0v=gpB[0*ST]; b1v=gpB[1*ST]; b2v=gpB[2*ST]; b3v=gpB[3*ST];
    }

#define PSTEP(F, GP, SS, BASE, BUF, CC, HS, HO, RQ) { \
    float2 nf = GP[(size_t)((BASE)+(SS)+4)*ST]; /* <= gx[NT+3]: in-bounds scratch */ \
    float x0 = fmaf(wS0,HS, fmaf(wO0,HO, F.x)); \
    float x1 = fmaf(wS1,HS, fmaf(wO1,HO, F.y)); \
    GATE_COMBINE(x0, x1, CC, HS, HO) \
    h0buf[BUF][SS][RQ][e] = HS; \
    F = nf; }

#define CSTEP(SS, BASE, BUF, CC, HS, HO, RQ, ROW) { \
    const float2 h0v = *(const float2*)&h0buf[BUF][SS][RQ][0]; \
    float x0 = fmaf(whS0,HS, fmaf(whO0,HO, fmaf(wi00,h0v.x, fmaf(wi01,h0v.y, bb0)))); \
    float x1 = fmaf(whS1,HS, fmaf(whO1,HO, fmaf(wi10,h0v.x, fmaf(wi11,h0v.y, bb1)))); \
    GATE_COMBINE(x0, x1, CC, HS, HO) \
    y1out[((size_t)((BASE)+(SS))*NB + (ROW))*2 + e] = HS; }

    for (int cidx=0; cidx<=NT/CHUNK; ++cidx){
        if (wv==0){
            if (cidx < NT/CHUNK){
                const int buf = cidx & 1;
                const int base = cidx*CHUNK;
                for (int s=0; s<CHUNK; s+=4){
                    PSTEP(a0, gpA, s+0, base, buf, cA, hsA, hoA, q)
                    PSTEP(b0v, gpB, s+0, base, buf, cB, hsB, hoB, q+16)
                    PSTEP(a1, gpA, s+1, base, buf, cA, hsA, hoA, q)
                    PSTEP(b1v, gpB, s+1, base, buf, cB, hsB, hoB, q+16)
                    PSTEP(a2, gpA, s+2, base, buf, cA, hsA, hoA, q)
                    PSTEP(b2v, gpB, s+2, base, buf, cB, hsB, hoB, q+16)
                    PSTEP(a3, gpA, s+3, base, buf, cA, hsA, hoA, q)
                    PSTEP(b3v, gpB, s+3, base, buf, cB, hsB, hoB, q+16)
                }
            }
        } else {
            if (cidx >= 1){
                const int buf = (cidx-1) & 1;
                const int base = (cidx-1)*CHUNK;
#pragma unroll 4
                for (int s=0; s<CHUNK; ++s){
                    CSTEP(s, base, buf, cA, hsA, hoA, q,    rowA)
                    CSTEP(s, base, buf, cB, hsB, hoB, q+16, rowB)
                }
            }
        }
        __syncthreads();
    }
#undef PSTEP
#undef CSTEP
    const float csA = qp<QP_PAIR>(cA) * INV2L2E;   // unscale c (valid lanes 0,2)
    const float csB = qp<QP_PAIR>(cB) * INV2L2E;
    if (wv==0){
        tail[rowA*2+e]          = hsA;  tail[rowB*2+e]          = hsB;   // h_n[0]
        tail[2*NB*2 + rowA*2+e] = csA;  tail[2*NB*2 + rowB*2+e] = csB;   // c_n[0]
    } else {
        tail[NB*2 + rowA*2+e]   = hsA;  tail[NB*2 + rowB*2+e]   = hsB;   // h_n[1]
        tail[3*NB*2 + rowA*2+e] = csA;  tail[3*NB*2 + rowB*2+e] = csB;   // c_n[1]
    }
}

// K3: out[bt][j] = y1[bt]·Wfc[j] + bfc[j]; one float4 store per thread.
__global__ __launch_bounds__(256) void fc_out(const float* __restrict__ y1,
                                              const float* __restrict__ Wfc,
                                              const float* __restrict__ bfc,
                                              float* __restrict__ out){
    const int tid = threadIdx.x;
    const int j4  = tid & 31;
    const int btl = tid >> 5;
    const int bt  = blockIdx.x*8 + btl;
    const int b   = bt >> 11;
    const int tt  = bt & (NT-1);
    const float2 y  = *(const float2*)(y1 + ((size_t)tt*NB + b)*2);
    const float4 wa = *(const float4*)(Wfc + j4*8);
    const float4 wb = *(const float4*)(Wfc + j4*8+4);
    const float4 bbv= *(const float4*)(bfc + j4*4);
    float4 o;
    o.x = fmaf(y.x,wa.x, fmaf(y.y,wa.y, bbv.x));
    o.y = fmaf(y.x,wa.z, fmaf(y.y,wa.w, bbv.y));
    o.z = fmaf(y.x,wb.x, fmaf(y.y,wb.y, bbv.z));
    o.w = fmaf(y.x,wb.z, fmaf(y.y,wb.w, bbv.w));
    *(float4*)(out + (size_t)bt*128 + j4*4) = o;
}

extern "C" void kernel_launch(void* const* d_in, const int* in_sizes, int n_in,
                              void* d_out, int out_size, void* d_ws, size_t ws_size,
                              hipStream_t stream){
    const int*   x    = (const int*)d_in[0];
    const float* emb  = (const float*)d_in[1];
    const float* Wih0 = (const float*)d_in[2];
    const float* Whh0 = (const float*)d_in[3];
    const float* b0   = (const float*)d_in[4];
    const float* Wih1 = (const float*)d_in[5];
    const float* Whh1 = (const float*)d_in[6];
    const float* b1   = (const float*)d_in[7];
    const float* Wfc  = (const float*)d_in[8];
    const float* bfc  = (const float*)d_in[9];
    float* out  = (float*)d_out;
    float* tab  = (float*)d_ws;                       // VOCAB*8 floats = 1.6 MB (ws)
    float* y1   = tab + (size_t)VOCAB*8;              // T*B*2 floats = 8 MB (ws)
    float* tail = out + (size_t)NB*NT*NOUT;           // h_n|c_n region of d_out
    float4* gxs = (float4*)d_out;                     // 33.6 MB scratch in d_out; dead before fc_out writes

    build_table<<<(VOCAB+255)/256, 256, 0, stream>>>(emb, Wih0, b0, tab);
    expand_gates<<<(NB*NT)/256, 256, 0, stream>>>(x, tab, gxs);
    lstm_pipe<<<16, 128, 0, stream>>>((const float2*)gxs, Whh0, Wih1, Whh1, b1, y1, tail);
    fc_out<<<(NB*NT)/8, 256, 0, stream>>>(y1, Wfc, bfc, out);
}

// Round 12
// 341.640 us; speedup vs baseline: 1.2152x; 1.2152x over previous
//
#include <hip/hip_runtime.h>

#define VOCAB 50257
#define NB 512
#define NT 2048
#define NOUT 128
#define CHUNK 32
#define L2E 1.4426950408889634f
#define INV2L2E 0.34657359027997264f   // ln2/2

// DPP controls
#define DPP_XOR1 0xB1   // quad_perm [1,0,3,2]
#define DPP_B0   0x00   // quad_perm [0,0,0,0]
#define DPP_B2   0xAA   // quad_perm [2,2,2,2]
#define DPP_B3   0xFF   // quad_perm [3,3,3,3]
#define DPP_HMIR 0x141  // row_half_mirror (swap 8-lane halves' quads)

template<int CTRL>
__device__ __forceinline__ float qp(float v){
    return __int_as_float(__builtin_amdgcn_update_dpp(0, __float_as_int(v), CTRL, 0xF, 0xF, true));
}

// Gate-lane layout: l=0..7 -> (gi = l&3, e = l>>2); gi order {i,g,f,o};
// PyTorch row rj: i=e, g=4+e, f=2+e, o=6+e. Scale s: g-> +2*L2E, others -> -L2E.
__device__ __forceinline__ int gate_rj(int gi, int e){
    return (gi==0) ? e : (gi==1) ? 4+e : (gi==2) ? 2+e : 6+e;
}

// K1: tab[v][l] = s(l) * (b0[rj(l)] + emb[v]·Wih0[rj(l)])
__global__ __launch_bounds__(256) void build_table(const float* __restrict__ emb,
                                                   const float* __restrict__ Wih0,
                                                   const float* __restrict__ b0,
                                                   float* __restrict__ tab){
    int v = blockIdx.x*256 + threadIdx.x;
    if (v >= VOCAB) return;
    const float4* ep = (const float4*)(emb + (size_t)v*8);
    float4 e0 = ep[0], e1 = ep[1];
    float e[8] = {e0.x,e0.y,e0.z,e0.w,e1.x,e1.y,e1.z,e1.w};
    float o[8];
#pragma unroll
    for (int l=0;l<8;l++){
        int gi = l&3, el = l>>2;
        int rj = gate_rj(gi, el);
        float s = b0[rj];
#pragma unroll
        for (int d=0;d<8;d++) s = fmaf(e[d], Wih0[rj*8+d], s);
        o[l] = s * ((gi==1) ? 2.0f*L2E : -L2E);
    }
    float4* tp = (float4*)(tab + (size_t)v*8);
    tp[0] = make_float4(o[0],o[1],o[2],o[3]);
    tp[1] = make_float4(o[4],o[5],o[6],o[7]);
}

// K1b: gx[t][b][0..7] = tab[x[b][t]][0..7] — parallel gather on all CUs.
__global__ __launch_bounds__(256) void expand_gates(const int* __restrict__ x,
                                                    const float* __restrict__ tab,
                                                    float4* __restrict__ gx){
    int gid = blockIdx.x*256 + threadIdx.x;   // [0, B*T)
    int t = gid >> 9;
    int b = gid & (NB-1);
    int tok = x[(size_t)b*NT + t];
    const float4* tp = (const float4*)tab + (size_t)tok*2;
    float4 v0 = tp[0], v1 = tp[1];
    gx[(size_t)gid*2]   = v0;
    gx[(size_t)gid*2+1] = v1;
}

// 8-lane gate step: one exp2+rcp instr covers all gates; c replicated on all
// 4 lanes of the quad (pre-scaled by 2*L2E). HOwn/HOth = h of own/other elem.
#define GATE8(x, CC, HOwn, HOth) { \
    float ex = __builtin_amdgcn_exp2f(x); \
    float r  = __builtin_amdgcn_rcpf(1.0f+ex); \
    float v  = fmaf(Bc, r, Ac); \
    float u  = qp<DPP_XOR1>(v); \
    float pr = v*u;                       /* lanes 0/1: i*ghat */ \
    float prb= qp<DPP_B0>(pr); \
    float fv = qp<DPP_B2>(v); \
    CC = fmaf(fv, CC, prb); \
    float e2 = __builtin_amdgcn_exp2f(CC); \
    float r2 = __builtin_amdgcn_rcpf(1.0f+e2); \
    float th = fmaf(-2.0f, r2, 1.0f); \
    float ov = qp<DPP_B3>(v); \
    float hh = ov*th;                     /* h replicated in quad */ \
    HOwn = hh; \
    HOth = qp<DPP_HMIR>(hh); }

// K2: layer-pipelined scan, 8 lanes/row. Block = 128 thr = 2 waves; 8 rows/block.
// wave0 = layer0: reads gx, computes h0, STAGES layer-1 input projection
// xpre = s*(b1 + Wih1·h0) into LDS. wave1 = layer1: x = wh·h1 + xpre.
__global__ __launch_bounds__(128) void lstm_pipe(const float* __restrict__ gx,
                                                 const float* __restrict__ Whh0,
                                                 const float* __restrict__ Wih1,
                                                 const float* __restrict__ Whh1,
                                                 const float* __restrict__ b1,
                                                 float* __restrict__ y1out,   // [T][B][2]
                                                 float* __restrict__ tail){
    __shared__ float xpre[2][CHUNK][8][8];    // 16 KB double buffer
    const int tid  = threadIdx.x;
    const int wv   = tid >> 6;
    const int lane = tid & 63;
    const int l    = lane & 7;
    const int q    = lane >> 3;               // 0..7 rows per wave
    const int row  = blockIdx.x*8 + q;
    const int gi   = l & 3;
    const int e    = l >> 2;
    const int rj   = gate_rj(gi, e);
    const float s  = (gi==1) ? 2.0f*L2E : -L2E;
    const float Ac = (gi==1) ? 2.0f*L2E : 0.0f;
    const float Bc = (gi==1) ? -4.0f*L2E : 1.0f;

    // wave0: layer0 recurrent weights + layer1 input-projection weights
    const float wOwn0 = Whh0[rj*2+e]*s,     wOth0 = Whh0[rj*2+(e^1)]*s;
    const float wiOwn = Wih1[rj*2+e]*s,     wiOth = Wih1[rj*2+(e^1)]*s;
    const float bb    = b1[rj]*s;
    // wave1: layer1 recurrent weights
    const float whOwn = Whh1[rj*2+e]*s,     whOth = Whh1[rj*2+(e^1)]*s;

    float hOwn=0.f, hOth=0.f, c=0.f;
    const size_t ST = (size_t)NB*8;           // float stride per t
    const float* __restrict__ gp = gx + (size_t)row*8 + l;
    float a0=0.f,a1=0.f,a2=0.f,a3=0.f;        // 4-deep prefetch (wave0)
    if (wv==0){ a0=gp[0*ST]; a1=gp[1*ST]; a2=gp[2*ST]; a3=gp[3*ST]; }
    const bool st = (gi==0);                  // store lane (one per quad)

#define PSTEP(F, SS, BASE, BUF) { \
    float nf = gp[(size_t)((BASE)+(SS)+4)*ST]; /* <= gx[NT+3]: in-bounds scratch */ \
    float x = fmaf(wOwn0,hOwn, fmaf(wOth0,hOth, F)); \
    GATE8(x, c, hOwn, hOth) \
    float xp = fmaf(wiOwn,hOwn, fmaf(wiOth,hOth, bb)); \
    xpre[BUF][SS][q][l] = xp; \
    F = nf; }

#define CSTEP(SS, BASE, BUF) { \
    float xv = xpre[BUF][SS][q][l]; \
    float x = fmaf(whOwn,hOwn, fmaf(whOth,hOth, xv)); \
    GATE8(x, c, hOwn, hOth) \
    if (st) y1out[((size_t)((BASE)+(SS))*NB + row)*2 + e] = hOwn; }

    for (int cidx=0; cidx<=NT/CHUNK; ++cidx){
        if (wv==0){
            if (cidx < NT/CHUNK){
                const int buf = cidx & 1;
                const int base = cidx*CHUNK;
                for (int ss=0; ss<CHUNK; ss+=4){
                    PSTEP(a0, ss+0, base, buf)
                    PSTEP(a1, ss+1, base, buf)
                    PSTEP(a2, ss+2, base, buf)
                    PSTEP(a3, ss+3, base, buf)
                }
            }
        } else {
            if (cidx >= 1){
                const int buf = (cidx-1) & 1;
                const int base = (cidx-1)*CHUNK;
#pragma unroll 8
                for (int ss=0; ss<CHUNK; ++ss){
                    CSTEP(ss, base, buf)
                }
            }
        }
        __syncthreads();
    }
#undef PSTEP
#undef CSTEP
    if (st){
        const float cs = c * INV2L2E;
        if (wv==0){
            tail[row*2+e]          = hOwn;   // h_n[0]
            tail[2*NB*2 + row*2+e] = cs;     // c_n[0]
        } else {
            tail[NB*2 + row*2+e]   = hOwn;   // h_n[1]
            tail[3*NB*2 + row*2+e] = cs;     // c_n[1]
        }
    }
}

// K3: out[bt][j] = y1[bt]·Wfc[j] + bfc[j]; one float4 store per thread.
__global__ __launch_bounds__(256) void fc_out(const float* __restrict__ y1,
                                              const float* __restrict__ Wfc,
                                              const float* __restrict__ bfc,
                                              float* __restrict__ out){
    const int tid = threadIdx.x;
    const int j4  = tid & 31;
    const int btl = tid >> 5;
    const int bt  = blockIdx.x*8 + btl;
    const int b   = bt >> 11;
    const int tt  = bt & (NT-1);
    const float2 y  = *(const float2*)(y1 + ((size_t)tt*NB + b)*2);
    const float4 wa = *(const float4*)(Wfc + j4*8);
    const float4 wb = *(const float4*)(Wfc + j4*8+4);
    const float4 bbv= *(const float4*)(bfc + j4*4);
    float4 o;
    o.x = fmaf(y.x,wa.x, fmaf(y.y,wa.y, bbv.x));
    o.y = fmaf(y.x,wa.z, fmaf(y.y,wa.w, bbv.y));
    o.z = fmaf(y.x,wb.x, fmaf(y.y,wb.y, bbv.z));
    o.w = fmaf(y.x,wb.z, fmaf(y.y,wb.w, bbv.w));
    *(float4*)(out + (size_t)bt*128 + j4*4) = o;
}

extern "C" void kernel_launch(void* const* d_in, const int* in_sizes, int n_in,
                              void* d_out, int out_size, void* d_ws, size_t ws_size,
                              hipStream_t stream){
    const int*   x    = (const int*)d_in[0];
    const float* emb  = (const float*)d_in[1];
    const float* Wih0 = (const float*)d_in[2];
    const float* Whh0 = (const float*)d_in[3];
    const float* b0   = (const float*)d_in[4];
    const float* Wih1 = (const float*)d_in[5];
    const float* Whh1 = (const float*)d_in[6];
    const float* b1   = (const float*)d_in[7];
    const float* Wfc  = (const float*)d_in[8];
    const float* bfc  = (const float*)d_in[9];
    float* out  = (float*)d_out;
    float* tab  = (float*)d_ws;                       // VOCAB*8 floats = 1.6 MB (ws)
    float* y1   = tab + (size_t)VOCAB*8;              // T*B*2 floats = 8 MB (ws)
    float* tail = out + (size_t)NB*NT*NOUT;           // h_n|c_n region of d_out
    float4* gxs = (float4*)d_out;                     // 33.6 MB scratch in d_out; dead before fc_out writes

    build_table<<<(VOCAB+255)/256, 256, 0, stream>>>(emb, Wih0, b0, tab);
    expand_gates<<<(NB*NT)/256, 256, 0, stream>>>(x, tab, gxs);
    lstm_pipe<<<64, 128, 0, stream>>>((const float*)gxs, Whh0, Wih1, Whh1, b1, y1, tail);
    fc_out<<<(NB*NT)/8, 256, 0, stream>>>(y1, Wfc, bfc, out);
}